// Round 1
// baseline (202.901 us; speedup 1.0000x reference)
//
#include <hip/hip_runtime.h>

// ShapeAwarePhaseAwareLoss: out = 2/(B*D) * sum_{b,d} factor[b] * ((sp-st)^2 + (cp-ct)^2)
// factor[b] = shape_types[b] < 0.5 ? 1.0 : 1.3
// B=4096, D=16384, fp32 inputs. Memory-bound streaming reduction (1 GiB read).

constexpr int B_DIM = 4096;
constexpr int D_DIM = 16384;
constexpr int NVEC_SHIFT = 12;            // D/4 = 4096 = 2^12 float4s per row
constexpr long long NVEC = (long long)B_DIM * D_DIM / 4;  // 16,777,216
constexpr int NBLOCKS = 2048;             // 256 CU * 8 blocks/CU
constexpr int NTHREADS = 256;

__global__ __launch_bounds__(NTHREADS) void phase_loss_partial(
    const float4* __restrict__ sp, const float4* __restrict__ cp,
    const float4* __restrict__ st, const float4* __restrict__ ct,
    const float* __restrict__ shape_types, float* __restrict__ partials)
{
    float acc = 0.0f;
    const long long stride = (long long)gridDim.x * blockDim.x;
    for (long long i = (long long)blockIdx.x * blockDim.x + threadIdx.x; i < NVEC; i += stride) {
        const int row = (int)(i >> NVEC_SHIFT);
        const float f = (shape_types[row] < 0.5f) ? 1.0f : 1.3f;
        const float4 a = sp[i];
        const float4 b = st[i];
        const float4 c = cp[i];
        const float4 d = ct[i];
        const float dx0 = a.x - b.x, dx1 = a.y - b.y, dx2 = a.z - b.z, dx3 = a.w - b.w;
        const float dy0 = c.x - d.x, dy1 = c.y - d.y, dy2 = c.z - d.z, dy3 = c.w - d.w;
        float s = dx0 * dx0;
        s = fmaf(dx1, dx1, s);
        s = fmaf(dx2, dx2, s);
        s = fmaf(dx3, dx3, s);
        s = fmaf(dy0, dy0, s);
        s = fmaf(dy1, dy1, s);
        s = fmaf(dy2, dy2, s);
        s = fmaf(dy3, dy3, s);
        acc = fmaf(f, s, acc);
    }

    // wave64 reduction
    #pragma unroll
    for (int off = 32; off > 0; off >>= 1)
        acc += __shfl_down(acc, off, 64);

    // cross-wave reduction via LDS (256 threads = 4 waves)
    __shared__ float wsum[NTHREADS / 64];
    const int lane = threadIdx.x & 63;
    const int wave = threadIdx.x >> 6;
    if (lane == 0) wsum[wave] = acc;
    __syncthreads();
    if (threadIdx.x == 0) {
        float t = wsum[0] + wsum[1] + wsum[2] + wsum[3];
        partials[blockIdx.x] = t;
    }
}

__global__ __launch_bounds__(NTHREADS) void phase_loss_final(
    const float* __restrict__ partials, float* __restrict__ out)
{
    float acc = 0.0f;
    for (int i = threadIdx.x; i < NBLOCKS; i += NTHREADS)
        acc += partials[i];

    #pragma unroll
    for (int off = 32; off > 0; off >>= 1)
        acc += __shfl_down(acc, off, 64);

    __shared__ float wsum[NTHREADS / 64];
    const int lane = threadIdx.x & 63;
    const int wave = threadIdx.x >> 6;
    if (lane == 0) wsum[wave] = acc;
    __syncthreads();
    if (threadIdx.x == 0) {
        const float total = wsum[0] + wsum[1] + wsum[2] + wsum[3];
        const float scale = 2.0f / ((float)B_DIM * (float)D_DIM);  // PHASE_WEIGHT / (B*D)
        out[0] = scale * total;
    }
}

extern "C" void kernel_launch(void* const* d_in, const int* in_sizes, int n_in,
                              void* d_out, int out_size, void* d_ws, size_t ws_size,
                              hipStream_t stream) {
    const float4* sp = (const float4*)d_in[0];  // phase_sin_pred
    const float4* cp = (const float4*)d_in[1];  // phase_cos_pred
    const float4* st = (const float4*)d_in[2];  // phase_sin_true
    const float4* ct = (const float4*)d_in[3];  // phase_cos_true
    const float* shape_types = (const float*)d_in[4];
    float* out = (float*)d_out;
    float* partials = (float*)d_ws;  // NBLOCKS floats = 8 KiB

    phase_loss_partial<<<NBLOCKS, NTHREADS, 0, stream>>>(sp, cp, st, ct, shape_types, partials);
    phase_loss_final<<<1, NTHREADS, 0, stream>>>(partials, out);
}

// Round 2
// 192.252 us; speedup vs baseline: 1.0554x; 1.0554x over previous
//
#include <hip/hip_runtime.h>

// ShapeAwarePhaseAwareLoss: out = 2/(B*D) * sum_{b,d} factor[b] * ((sp-st)^2 + (cp-ct)^2)
// factor[b] = shape_types[b] < 0.5 ? 1.0 : 1.3
// B=4096, D=16384, fp32. Streaming reduction, 1 GiB read.
// Round 2: block-per-2-rows layout, hoisted factor, 4x unroll for 16 in-flight
// float4 loads per thread (MLP was the round-1 limiter: 27% HBM, VALUBusy 5%).

constexpr int B_DIM = 4096;
constexpr int D_DIM = 16384;
constexpr int ROW_VECS = D_DIM / 4;       // 4096 float4 per row
constexpr int ROWS_PER_BLOCK = 2;
constexpr int NBLOCKS = B_DIM / ROWS_PER_BLOCK;  // 2048
constexpr int NTHREADS = 256;
constexpr int ITERS = ROW_VECS / NTHREADS;       // 16 float4 per thread per row

__device__ __forceinline__ float sq_diff_acc(float4 a, float4 b, float s) {
    s = fmaf(a.x - b.x, a.x - b.x, s);
    s = fmaf(a.y - b.y, a.y - b.y, s);
    s = fmaf(a.z - b.z, a.z - b.z, s);
    s = fmaf(a.w - b.w, a.w - b.w, s);
    return s;
}

__global__ __launch_bounds__(NTHREADS) void phase_loss_partial(
    const float4* __restrict__ sp, const float4* __restrict__ cp,
    const float4* __restrict__ st, const float4* __restrict__ ct,
    const float* __restrict__ shape_types, float* __restrict__ partials)
{
    float block_acc = 0.0f;

    #pragma unroll
    for (int r = 0; r < ROWS_PER_BLOCK; ++r) {
        const int row = blockIdx.x * ROWS_PER_BLOCK + r;
        const float f = (shape_types[row] < 0.5f) ? 1.0f : 1.3f;
        const long long base = (long long)row * ROW_VECS;
        const float4* __restrict__ spr = sp + base;
        const float4* __restrict__ cpr = cp + base;
        const float4* __restrict__ str_ = st + base;
        const float4* __restrict__ ctr = ct + base;

        float s = 0.0f;
        #pragma unroll
        for (int it = 0; it < ITERS; it += 4) {
            const int idx = it * NTHREADS + threadIdx.x;
            // issue all 16 loads (4 per stream) before consuming
            const float4 a0 = spr[idx];
            const float4 a1 = spr[idx + NTHREADS];
            const float4 a2 = spr[idx + 2 * NTHREADS];
            const float4 a3 = spr[idx + 3 * NTHREADS];
            const float4 b0 = str_[idx];
            const float4 b1 = str_[idx + NTHREADS];
            const float4 b2 = str_[idx + 2 * NTHREADS];
            const float4 b3 = str_[idx + 3 * NTHREADS];
            const float4 c0 = cpr[idx];
            const float4 c1 = cpr[idx + NTHREADS];
            const float4 c2 = cpr[idx + 2 * NTHREADS];
            const float4 c3 = cpr[idx + 3 * NTHREADS];
            const float4 d0 = ctr[idx];
            const float4 d1 = ctr[idx + NTHREADS];
            const float4 d2 = ctr[idx + 2 * NTHREADS];
            const float4 d3 = ctr[idx + 3 * NTHREADS];

            s = sq_diff_acc(a0, b0, s);
            s = sq_diff_acc(a1, b1, s);
            s = sq_diff_acc(a2, b2, s);
            s = sq_diff_acc(a3, b3, s);
            s = sq_diff_acc(c0, d0, s);
            s = sq_diff_acc(c1, d1, s);
            s = sq_diff_acc(c2, d2, s);
            s = sq_diff_acc(c3, d3, s);
        }
        block_acc = fmaf(f, s, block_acc);
    }

    // wave64 reduction
    #pragma unroll
    for (int off = 32; off > 0; off >>= 1)
        block_acc += __shfl_down(block_acc, off, 64);

    __shared__ float wsum[NTHREADS / 64];
    const int lane = threadIdx.x & 63;
    const int wave = threadIdx.x >> 6;
    if (lane == 0) wsum[wave] = block_acc;
    __syncthreads();
    if (threadIdx.x == 0)
        partials[blockIdx.x] = wsum[0] + wsum[1] + wsum[2] + wsum[3];
}

__global__ __launch_bounds__(NTHREADS) void phase_loss_final(
    const float* __restrict__ partials, float* __restrict__ out)
{
    float acc = 0.0f;
    for (int i = threadIdx.x; i < NBLOCKS; i += NTHREADS)
        acc += partials[i];

    #pragma unroll
    for (int off = 32; off > 0; off >>= 1)
        acc += __shfl_down(acc, off, 64);

    __shared__ float wsum[NTHREADS / 64];
    const int lane = threadIdx.x & 63;
    const int wave = threadIdx.x >> 6;
    if (lane == 0) wsum[wave] = acc;
    __syncthreads();
    if (threadIdx.x == 0) {
        const float total = wsum[0] + wsum[1] + wsum[2] + wsum[3];
        const float scale = 2.0f / ((float)B_DIM * (float)D_DIM);  // PHASE_WEIGHT / (B*D)
        out[0] = scale * total;
    }
}

extern "C" void kernel_launch(void* const* d_in, const int* in_sizes, int n_in,
                              void* d_out, int out_size, void* d_ws, size_t ws_size,
                              hipStream_t stream) {
    const float4* sp = (const float4*)d_in[0];  // phase_sin_pred
    const float4* cp = (const float4*)d_in[1];  // phase_cos_pred
    const float4* st = (const float4*)d_in[2];  // phase_sin_true
    const float4* ct = (const float4*)d_in[3];  // phase_cos_true
    const float* shape_types = (const float*)d_in[4];
    float* out = (float*)d_out;
    float* partials = (float*)d_ws;  // NBLOCKS floats = 8 KiB

    phase_loss_partial<<<NBLOCKS, NTHREADS, 0, stream>>>(sp, cp, st, ct, shape_types, partials);
    phase_loss_final<<<1, NTHREADS, 0, stream>>>(partials, out);
}

// Round 3
// 189.646 us; speedup vs baseline: 1.0699x; 1.0137x over previous
//
#include <hip/hip_runtime.h>

// ShapeAwarePhaseAwareLoss: out = 2/(B*D) * sum_{b,d} factor[b] * ((sp-st)^2 + (cp-ct)^2)
// factor[b] = shape_types[b] < 0.5 ? 1.0 : 1.3
// B=4096, D=16384, fp32. Streaming reduction, 1 GiB read.
// Round 3: 8192 blocks (half-row each) -> 4 wave-slot fill rounds so CUs
// backfill instead of idling during drain (round-2 had exactly 1 fill round;
// measured occupancy 53-70% = drain average). 8 loads in flight per group,
// two independent accumulators, VGPR target ~32.

constexpr int B_DIM = 4096;
constexpr int D_DIM = 16384;
constexpr int ROW_VECS = D_DIM / 4;            // 4096 float4 per row
constexpr int HALF_VECS = ROW_VECS / 2;        // 2048 float4 per half-row
constexpr int NBLOCKS = B_DIM * 2;             // 8192 blocks, half-row each
constexpr int NTHREADS = 256;
constexpr int ITERS = HALF_VECS / NTHREADS;    // 8 float4 per thread per array

__device__ __forceinline__ float sq_diff_acc(float4 a, float4 b, float s) {
    s = fmaf(a.x - b.x, a.x - b.x, s);
    s = fmaf(a.y - b.y, a.y - b.y, s);
    s = fmaf(a.z - b.z, a.z - b.z, s);
    s = fmaf(a.w - b.w, a.w - b.w, s);
    return s;
}

__global__ __launch_bounds__(NTHREADS) void phase_loss_partial(
    const float4* __restrict__ sp, const float4* __restrict__ cp,
    const float4* __restrict__ st, const float4* __restrict__ ct,
    const float* __restrict__ shape_types, float* __restrict__ partials)
{
    const int row = blockIdx.x >> 1;
    const float f = (shape_types[row] < 0.5f) ? 1.0f : 1.3f;
    const long long base = (long long)blockIdx.x * HALF_VECS;

    float s0 = 0.0f, s1 = 0.0f;
    #pragma unroll
    for (int it = 0; it < ITERS; it += 2) {
        const long long idx0 = base + it * NTHREADS + threadIdx.x;
        const long long idx1 = idx0 + NTHREADS;
        // 8 independent loads in flight
        const float4 a0 = sp[idx0];
        const float4 b0 = st[idx0];
        const float4 c0 = cp[idx0];
        const float4 d0 = ct[idx0];
        const float4 a1 = sp[idx1];
        const float4 b1 = st[idx1];
        const float4 c1 = cp[idx1];
        const float4 d1 = ct[idx1];

        s0 = sq_diff_acc(a0, b0, s0);
        s0 = sq_diff_acc(c0, d0, s0);
        s1 = sq_diff_acc(a1, b1, s1);
        s1 = sq_diff_acc(c1, d1, s1);
    }
    float block_acc = f * (s0 + s1);

    // wave64 reduction
    #pragma unroll
    for (int off = 32; off > 0; off >>= 1)
        block_acc += __shfl_down(block_acc, off, 64);

    __shared__ float wsum[NTHREADS / 64];
    const int lane = threadIdx.x & 63;
    const int wave = threadIdx.x >> 6;
    if (lane == 0) wsum[wave] = block_acc;
    __syncthreads();
    if (threadIdx.x == 0)
        partials[blockIdx.x] = wsum[0] + wsum[1] + wsum[2] + wsum[3];
}

__global__ __launch_bounds__(NTHREADS) void phase_loss_final(
    const float* __restrict__ partials, float* __restrict__ out)
{
    float acc = 0.0f;
    for (int i = threadIdx.x; i < NBLOCKS; i += NTHREADS)
        acc += partials[i];

    #pragma unroll
    for (int off = 32; off > 0; off >>= 1)
        acc += __shfl_down(acc, off, 64);

    __shared__ float wsum[NTHREADS / 64];
    const int lane = threadIdx.x & 63;
    const int wave = threadIdx.x >> 6;
    if (lane == 0) wsum[wave] = acc;
    __syncthreads();
    if (threadIdx.x == 0) {
        const float total = wsum[0] + wsum[1] + wsum[2] + wsum[3];
        const float scale = 2.0f / ((float)B_DIM * (float)D_DIM);  // PHASE_WEIGHT / (B*D)
        out[0] = scale * total;
    }
}

extern "C" void kernel_launch(void* const* d_in, const int* in_sizes, int n_in,
                              void* d_out, int out_size, void* d_ws, size_t ws_size,
                              hipStream_t stream) {
    const float4* sp = (const float4*)d_in[0];  // phase_sin_pred
    const float4* cp = (const float4*)d_in[1];  // phase_cos_pred
    const float4* st = (const float4*)d_in[2];  // phase_sin_true
    const float4* ct = (const float4*)d_in[3];  // phase_cos_true
    const float* shape_types = (const float*)d_in[4];
    float* out = (float*)d_out;
    float* partials = (float*)d_ws;  // NBLOCKS floats = 32 KiB

    phase_loss_partial<<<NBLOCKS, NTHREADS, 0, stream>>>(sp, cp, st, ct, shape_types, partials);
    phase_loss_final<<<1, NTHREADS, 0, stream>>>(partials, out);
}